// Round 1
// 63.261 us; speedup vs baseline: 1.0169x; 1.0169x over previous
//
#include <hip/hip_runtime.h>

// Problem constants (from reference):
//   x  : (1, 24, 56, 56) f32
//   w0 : (96, 9, 14)     f32
//   w1 : (24, 2, 14)     f32   (flat [c][kj], kj = k*14+j, 28 wide)
//   out: (1, 96, 56, 56) f32
//
// Index algebra (derived from einsum/pad/unfold/roll/sum chain):
//   B[h][kj]   = sum_c x[c,m,h] * w1[c,kj]           (h in [0,56), zero outside)
//   S[kh,n,j]  = B[(n+kh-4)][j] + B[((n+55)%56 + kh - 4)][14+j]
//   out[i,m,n] = sum_{kh<9,j<14} w0[i,kh,j] * S[kh,n,j]
// B stored padded: hp = h+4 in [0,64), halo rows zeroed.
//
// This revision: 512-thread blocks (8 waves/CU = 2 waves/SIMD, up from 1) to
// hide LDS latency. Phase2b split across kh halves (threads 0-255: kh 0..4,
// threads 256-511: kh 5..8), merged through an LDS partial buffer aliased
// onto sx (dead after phase1). Phase1 uses 392 threads (2h x 2kj tiles).

#define MDIM 56
#define NDIM 56
#define CIN  24
#define JD   14
#define KJD  28
#define KHD  9
#define IOUT 96
#define ITILE 24
#define NT   512

__global__ __launch_bounds__(NT) void fused_shift_conv(
    const float* __restrict__ x,    // [24][56][56]
    const float* __restrict__ w0,   // [96][9][14]
    const float* __restrict__ w1,   // [24][28]
    float* __restrict__ out)        // [96][56][56]
{
    const int m     = blockIdx.x;   // 0..55
    const int itile = blockIdx.y;   // 0..3
    const int tid   = threadIdx.x;  // 0..511

    // All row strides are multiples of 14 floats = 56 B -> every row 8B-aligned.
    __shared__ __align__(16) float sx [CIN * MDIM];         // [c][h]      1344 (reused as spart)
    __shared__ __align__(16) float sw1[CIN * KJD];          // [c][kj]      672
    __shared__ __align__(16) float sw0[ITILE * KHD * JD];   // [il][kh][j] 3024
    __shared__ __align__(16) float sB [64 * KJD];           // [hp][kj]    1792
    __shared__ __align__(16) float sS [KHD * NDIM * JD];    // [kh][n][j]  7056

    // ---- stage inputs into LDS (float4) ------------------------------------
    {
        float4*       sx4  = (float4*)sx;
        float4*       sw14 = (float4*)sw1;
        float4*       sw04 = (float4*)sw0;
        float4*       sB4  = (float4*)sB;
        const float4* x4   = (const float4*)x;
        const float4* w14  = (const float4*)w1;
        const float4* w04  = (const float4*)w0;

        for (int e = tid; e < CIN * JD; e += NT) {           // 336 float4 of x
            int c = e / JD, t = e % JD;
            sx4[e] = x4[c * 784 + m * JD + t];               // x[c][m][4t..]
        }
        for (int e = tid; e < (CIN * KJD) / 4; e += NT)      // 168 float4
            sw14[e] = w14[e];
        for (int e = tid; e < (ITILE * KHD * JD) / 4; e += NT) // 756 float4
            sw04[e] = w04[itile * (ITILE * KHD * JD / 4) + e];
        // zero only sB halo rows hp in {0..3, 60..63}: 8 rows x 28 = 56 float4
        for (int e = tid; e < 56; e += NT) {
            int r = e / 7;
            int hp = r + (r >= 4 ? 56 : 0);
            sB4[hp * 7 + (e % 7)] = make_float4(0.f, 0.f, 0.f, 0.f);
        }
    }
    __syncthreads();

    // ---- phase 1: B[h][kj] = sum_c x[c,h] * w1[c,kj], tiled 2h x 2kj -------
    if (tid < 392) {                  // 28 h-groups x 14 kj-groups
        const int h0  = 2 * (tid / 14);
        const int kj0 = 2 * (tid % 14);

        float2 acc0 = make_float2(0.f, 0.f);
        float2 acc1 = make_float2(0.f, 0.f);
        #pragma unroll
        for (int c = 0; c < CIN; ++c) {
            float2 xv = *(const float2*)&sx[c * MDIM + h0];
            float2 wv = *(const float2*)&sw1[c * KJD + kj0];
            acc0.x += xv.x * wv.x;  acc0.y += xv.x * wv.y;
            acc1.x += xv.y * wv.x;  acc1.y += xv.y * wv.y;
        }
        *(float2*)&sB[(h0 + 4) * KJD + kj0] = acc0;   // hp = h+4
        *(float2*)&sB[(h0 + 5) * KJD + kj0] = acc1;
    }
    __syncthreads();

    // ---- phase 2a: S[kh][n][j] = B[n+kh][j] + B[h1+kh][14+j]  (float2) -----
    for (int e = tid; e < KHD * NDIM * 7; e += NT) {
        int kh = e / (NDIM * 7);
        int r  = e % (NDIM * 7);
        int n  = r / 7;
        int j2 = 2 * (r % 7);
        int h1 = (n + 55) % 56;
        float2 a = *(const float2*)&sB[(n  + kh) * KJD + j2];
        float2 b = *(const float2*)&sB[(h1 + kh) * KJD + JD + j2];
        *(float2*)&sS[(kh * NDIM + n) * JD + j2] = make_float2(a.x + b.x, a.y + b.y);
    }
    __syncthreads();

    // ---- phase 2b: out[i,m,n] = sum_{kh,j} w0[i,kh,j] * S[kh,n,j] ----------
    // Split over kh: half 0 (tid<256) does kh 0..4, half 1 does kh 5..8.
    // Within a half, thread t (<224): il0 = 3*(t%8), n0 = 2*(t/8).
    const int half = tid >> 8;
    const int t    = tid & 255;
    float* spart = sx;                 // 224*6 = 1344 floats; sx dead after phase1

    float acc[3][2] = {{0.f,0.f},{0.f,0.f},{0.f,0.f}};
    const int il0 = 3 * (t % 8);
    const int n0  = 2 * (t / 8);

    if (t < 224) {
        auto body = [&](int kh) {
            const float2* s0 = (const float2*)&sS[(kh * NDIM + n0    ) * JD];
            const float2* s1 = (const float2*)&sS[(kh * NDIM + n0 + 1) * JD];
            const float2* wa = (const float2*)&sw0[((il0 + 0) * KHD + kh) * JD];
            const float2* wb = (const float2*)&sw0[((il0 + 1) * KHD + kh) * JD];
            const float2* wc = (const float2*)&sw0[((il0 + 2) * KHD + kh) * JD];
            #pragma unroll
            for (int j2 = 0; j2 < 7; ++j2) {
                float2 v0 = s0[j2], v1 = s1[j2];
                float2 A = wa[j2], B = wb[j2], C = wc[j2];
                acc[0][0] += A.x * v0.x + A.y * v0.y;
                acc[0][1] += A.x * v1.x + A.y * v1.y;
                acc[1][0] += B.x * v0.x + B.y * v0.y;
                acc[1][1] += B.x * v1.x + B.y * v1.y;
                acc[2][0] += C.x * v0.x + C.y * v0.y;
                acc[2][1] += C.x * v1.x + C.y * v1.y;
            }
        };
        if (half == 0) {
            #pragma unroll
            for (int kh = 0; kh < 5; ++kh) body(kh);
        } else {
            #pragma unroll
            for (int kh = 5; kh < 9; ++kh) body(kh);
            // half 1 publishes partials (float2 stores, stride 6 words -> 2-way
            // bank aliasing only, free on CDNA4)
            float2* sp2 = (float2*)&spart[t * 6];
            sp2[0] = make_float2(acc[0][0], acc[0][1]);
            sp2[1] = make_float2(acc[1][0], acc[1][1]);
            sp2[2] = make_float2(acc[2][0], acc[2][1]);
        }
    }
    __syncthreads();

    if (half == 0 && t < 224) {
        const float2* sp2 = (const float2*)&spart[t * 6];
        #pragma unroll
        for (int a = 0; a < 3; ++a) {
            float2 p = sp2[a];
            int i = itile * ITILE + il0 + a;
            *(float2*)&out[(i * MDIM + m) * NDIM + n0] =
                make_float2(acc[a][0] + p.x, acc[a][1] + p.y);
        }
    }
}

extern "C" void kernel_launch(void* const* d_in, const int* in_sizes, int n_in,
                              void* d_out, int out_size, void* d_ws, size_t ws_size,
                              hipStream_t stream) {
    const float* x  = (const float*)d_in[0];
    const float* w0 = (const float*)d_in[1];
    const float* w1 = (const float*)d_in[2];
    float* out = (float*)d_out;

    dim3 grid(MDIM, IOUT / ITILE);  // (56, 4)
    dim3 block(NT);
    fused_shift_conv<<<grid, block, 0, stream>>>(x, w0, w1, out);
}